// Round 2
// baseline (6933.003 us; speedup 1.0000x reference)
//
#include <hip/hip_runtime.h>
#include <stdint.h>

typedef unsigned short u16;
typedef short v8s __attribute__((ext_vector_type(8)));
typedef float v4f __attribute__((ext_vector_type(4)));

#define DI static __device__ __forceinline__

DI u16 f2bf(float x){ union{float f; uint32_t u;} c; c.f = x; uint32_t r = c.u + 0x7fffu + ((c.u >> 16) & 1u); return (u16)(r >> 16); }
DI float bf2f(u16 b){ union{float f; uint32_t u;} c; c.u = ((uint32_t)b) << 16; return c.f; }
DI float gelu_f(float x){ return 0.5f * x * (1.0f + erff(x * 0.70710678118654752f)); }
DI float sigm(float x){ return 1.0f / (1.0f + expf(-x)); }

DI float gru_out(float i0, float i1, float i2, float g0, float g1, float g2,
                 float b0, float b1, float b2, float hprev)
{
    float r = sigm(i0 + g0 + b0);
    float z = sigm(i1 + g1 + b1);
    float n = tanhf(i2 + r * (g2 + b2));
    return (1.f - z) * n + z * hprev;
}

// Device-scope grid barrier: one fresh counter per barrier instance (no reset).
DI void grid_barrier(unsigned* cnt, int id, unsigned nblocks)
{
    __syncthreads();
    if (threadIdx.x == 0) {
        __threadfence();
        __hip_atomic_fetch_add(&cnt[id], 1u, __ATOMIC_RELEASE, __HIP_MEMORY_SCOPE_AGENT);
        while (__hip_atomic_load(&cnt[id], __ATOMIC_ACQUIRE, __HIP_MEMORY_SCOPE_AGENT) < nblocks) {
            __builtin_amdgcn_s_sleep(1);
        }
    }
    __syncthreads();
}

// ---------------------------------------------------------------------------
// Transpose + bf16 hi/lo split: W (K x N, f32) -> hi,lo (N x K, bf16 bits)
// ---------------------------------------------------------------------------
__global__ __launch_bounds__(256) void transpose_split_kernel(
    const float* __restrict__ W, u16* __restrict__ hi, u16* __restrict__ lo, int K, int N)
{
    __shared__ float t[32][33];
    int n0 = blockIdx.x * 32, k0 = blockIdx.y * 32;
    int tx = threadIdx.x & 31, ty = threadIdx.x >> 5;
    #pragma unroll
    for (int i = 0; i < 4; i++) {
        int k = k0 + ty + i * 8, n = n0 + tx;
        float v = (k < K && n < N) ? W[(size_t)k * N + n] : 0.f;
        t[ty + i * 8][tx] = v;
    }
    __syncthreads();
    #pragma unroll
    for (int i = 0; i < 4; i++) {
        int n = n0 + ty + i * 8, k = k0 + tx;
        if (n < N && k < K) {
            float v = t[tx][ty + i * 8];
            u16 h = f2bf(v);
            hi[(size_t)n * K + k] = h;
            lo[(size_t)n * K + k] = f2bf(v - bf2f(h));
        }
    }
}

// f32 transpose: W (K x N) -> WT (N x K)
__global__ __launch_bounds__(256) void transpose_f32_kernel(
    const float* __restrict__ W, float* __restrict__ WT, int K, int N)
{
    __shared__ float t[32][33];
    int n0 = blockIdx.x * 32, k0 = blockIdx.y * 32;
    int tx = threadIdx.x & 31, ty = threadIdx.x >> 5;
    #pragma unroll
    for (int i = 0; i < 4; i++) {
        int k = k0 + ty + i * 8, n = n0 + tx;
        t[ty + i * 8][tx] = (k < K && n < N) ? W[(size_t)k * N + n] : 0.f;
    }
    __syncthreads();
    #pragma unroll
    for (int i = 0; i < 4; i++) {
        int n = n0 + ty + i * 8, k = k0 + tx;
        if (n < N && k < K) WT[(size_t)n * K + k] = t[tx][ty + i * 8];
    }
}

// ---------------------------------------------------------------------------
// Embedding gathers + zero-init h buffers + zero barrier counters
// ---------------------------------------------------------------------------
__global__ __launch_bounds__(256) void gather_init_kernel(
    const int* __restrict__ src, const int* __restrict__ trg,
    const float* __restrict__ enc_embed, const float* __restrict__ dec_embed,
    float* __restrict__ embE, float* __restrict__ embD,
    float* __restrict__ hF0, float* __restrict__ hB0, unsigned* __restrict__ bar)
{
    int r = blockIdx.x, tx = threadIdx.x;
    if (r < 2048) {
        int idx = src[r];
        embE[(size_t)r * 256 + tx] = enc_embed[(size_t)idx * 256 + tx];
    } else if (r < 4064) {
        int rd = r - 2048;
        int t = rd >> 5, b = rd & 31;
        int tok = trg[b * 64 + t];
        embD[(size_t)rd * 256 + tx] = dec_embed[(size_t)tok * 256 + tx];
    } else if (r < 4192) {
        int i = (r - 4064) * 256 + tx;
        if (i < 16384) hF0[i] = 0.f; else hB0[i - 16384] = 0.f;
    } else {
        bar[tx] = 0u;
    }
}

// ---------------------------------------------------------------------------
// GEMM: C = act(A @ B + bias).  3-MFMA compensated bf16.  Block ids remapped
// m-fastest so the concurrent front shares B tiles (L2 locality).
// ---------------------------------------------------------------------------
__global__ __launch_bounds__(256) void gemm_bf16x3_kernel(
    const float* __restrict__ A, const u16* __restrict__ Bhi, const u16* __restrict__ Blo,
    const float* __restrict__ bias, float* __restrict__ C,
    int M, int N, int K, int act_gelu, int remap)
{
    __shared__ u16 Ah[128 * 40], Al[128 * 40], Bh[128 * 40], Bl[128 * 40];
    const int tid = threadIdx.x;
    const int lane = tid & 63, wave = tid >> 6;
    const int lm = lane & 15, quad = lane >> 4;
    const int wm = wave >> 1, wn = wave & 1;
    const int bid = blockIdx.y * gridDim.x + blockIdx.x;
    const int mt = bid % gridDim.y, nt_ = bid / gridDim.y;
    const int m0 = mt * 128, n0 = nt_ * 128;
    const int sr = tid >> 1;
    const int sh = (tid & 1) * 16;

    v4f acc[4][4];
    #pragma unroll
    for (int i = 0; i < 4; i++)
        #pragma unroll
        for (int j = 0; j < 4; j++)
            #pragma unroll
            for (int r = 0; r < 4; r++) acc[i][j][r] = 0.f;

    for (int k0 = 0; k0 < K; k0 += 32) {
        {
            float v[16];
            const int gm = m0 + sr;
            if (gm < M) {
                const float4* p = (const float4*)(A + (size_t)gm * K + k0 + sh);
                #pragma unroll
                for (int i = 0; i < 4; i++) {
                    float4 q = p[i];
                    v[4*i] = q.x; v[4*i+1] = q.y; v[4*i+2] = q.z; v[4*i+3] = q.w;
                }
            } else {
                #pragma unroll
                for (int i = 0; i < 16; i++) v[i] = 0.f;
            }
            v8s h0, h1, l0, l1;
            #pragma unroll
            for (int i = 0; i < 8; i++) {
                u16 ha = f2bf(v[i]);     u16 la = f2bf(v[i] - bf2f(ha));
                u16 hb = f2bf(v[8+i]);   u16 lb = f2bf(v[8+i] - bf2f(hb));
                h0[i] = (short)ha; l0[i] = (short)la; h1[i] = (short)hb; l1[i] = (short)lb;
            }
            *(v8s*)&Ah[sr * 40 + sh] = h0; *(v8s*)&Ah[sr * 40 + sh + 8] = h1;
            *(v8s*)&Al[sr * 40 + sh] = l0; *(v8s*)&Al[sr * 40 + sh + 8] = l1;
        }
        {
            const int gn = n0 + sr;
            v8s b0, b1, c0, c1;
            if (gn < N) {
                const v8s* ph = (const v8s*)(Bhi + (size_t)gn * K + k0 + sh);
                const v8s* pl = (const v8s*)(Blo + (size_t)gn * K + k0 + sh);
                b0 = ph[0]; b1 = ph[1]; c0 = pl[0]; c1 = pl[1];
            } else {
                #pragma unroll
                for (int i = 0; i < 8; i++) { b0[i] = 0; b1[i] = 0; c0[i] = 0; c1[i] = 0; }
            }
            *(v8s*)&Bh[sr * 40 + sh] = b0; *(v8s*)&Bh[sr * 40 + sh + 8] = b1;
            *(v8s*)&Bl[sr * 40 + sh] = c0; *(v8s*)&Bl[sr * 40 + sh + 8] = c1;
        }
        __syncthreads();
        v8s ah[4], al[4], bh[4], bl[4];
        #pragma unroll
        for (int mt2 = 0; mt2 < 4; mt2++) {
            int off = (wm * 64 + mt2 * 16 + lm) * 40 + quad * 8;
            ah[mt2] = *(v8s*)&Ah[off]; al[mt2] = *(v8s*)&Al[off];
        }
        #pragma unroll
        for (int nt2 = 0; nt2 < 4; nt2++) {
            int off = (wn * 64 + nt2 * 16 + lm) * 40 + quad * 8;
            bh[nt2] = *(v8s*)&Bh[off]; bl[nt2] = *(v8s*)&Bl[off];
        }
        #pragma unroll
        for (int mt2 = 0; mt2 < 4; mt2++)
            #pragma unroll
            for (int nt2 = 0; nt2 < 4; nt2++) {
                v4f a = acc[mt2][nt2];
                a = __builtin_amdgcn_mfma_f32_16x16x32_bf16(ah[mt2], bh[nt2], a, 0, 0, 0);
                a = __builtin_amdgcn_mfma_f32_16x16x32_bf16(ah[mt2], bl[nt2], a, 0, 0, 0);
                a = __builtin_amdgcn_mfma_f32_16x16x32_bf16(al[mt2], bh[nt2], a, 0, 0, 0);
                acc[mt2][nt2] = a;
            }
        __syncthreads();
    }
    #pragma unroll
    for (int nt2 = 0; nt2 < 4; nt2++) {
        int col = n0 + wn * 64 + nt2 * 16 + lm;
        if (col >= N) continue;
        float bv = bias ? bias[col] : 0.f;
        #pragma unroll
        for (int mt2 = 0; mt2 < 4; mt2++) {
            int rbase = m0 + wm * 64 + mt2 * 16 + quad * 4;
            #pragma unroll
            for (int r = 0; r < 4; r++) {
                int row = rbase + r;
                if (row < M) {
                    float v = acc[mt2][nt2][r] + bv;
                    if (act_gelu) v = gelu_f(v);
                    size_t drow = remap ? (size_t)((row & 31) * 64 + (row >> 5) + 1) : (size_t)row;
                    C[drow * (size_t)N + col] = v;
                }
            }
        }
    }
}

// ---------------------------------------------------------------------------
// Shared inner loop of the recurrent cells: acc[g][i] += h[b_i,:] . WhT[col_g,:]
// wl: LDS weights, layout c*580 + (k>>6)*72 + ((k>>5)&1)*36 + (k&31), c=gate*4+jj
// hl: LDS h half, layout b*292 + kseg*36 + kk   (kseg = k_local>>5)
// Thread map: tid = (bq<<5)|(jj<<3)|kseg; covers 4 batches (bq*4+i), col jb+jj,
// 3 gates, k in [half*256 + kseg*32, +32). Partials reduced over kseg by shfl.
// ---------------------------------------------------------------------------
DI void recur_mm(const float* __restrict__ hin, const float* __restrict__ wl,
                 float* __restrict__ hl, int tid, int jj, int kseg, int bq,
                 float acc[3][4])
{
    #pragma unroll
    for (int half = 0; half < 2; half++) {
        __syncthreads();
        #pragma unroll
        for (int it = 0; it < 8; it++) {
            int q = tid + it * 256;
            int b = q >> 6, kl = (q & 63) * 4;
            float4 v = *(const float4*)(hin + b * 512 + half * 256 + kl);
            *(float4*)&hl[b * 292 + (kl >> 5) * 36 + (kl & 31)] = v;
        }
        __syncthreads();
        const int wko = (half * 4 + (kseg >> 1)) * 72 + (kseg & 1) * 36;
        const float* w0 = &wl[jj * 580 + wko];
        const float* w1 = &wl[(4 + jj) * 580 + wko];
        const float* w2 = &wl[(8 + jj) * 580 + wko];
        const float* h0 = &hl[(bq * 4) * 292 + kseg * 36];
        const float* h1 = h0 + 292;
        const float* h2 = h1 + 292;
        const float* h3 = h2 + 292;
        #pragma unroll
        for (int kk = 0; kk < 32; kk += 4) {
            float4 a0 = *(const float4*)(w0 + kk);
            float4 a1 = *(const float4*)(w1 + kk);
            float4 a2 = *(const float4*)(w2 + kk);
            float4 hv0 = *(const float4*)(h0 + kk);
            float4 hv1 = *(const float4*)(h1 + kk);
            float4 hv2 = *(const float4*)(h2 + kk);
            float4 hv3 = *(const float4*)(h3 + kk);
#define ACC4(g, i, av, hv) acc[g][i] = fmaf(hv.w, av.w, fmaf(hv.z, av.z, fmaf(hv.y, av.y, fmaf(hv.x, av.x, acc[g][i]))))
            ACC4(0,0,a0,hv0); ACC4(1,0,a1,hv0); ACC4(2,0,a2,hv0);
            ACC4(0,1,a0,hv1); ACC4(1,1,a1,hv1); ACC4(2,1,a2,hv1);
            ACC4(0,2,a0,hv2); ACC4(1,2,a1,hv2); ACC4(2,2,a2,hv2);
            ACC4(0,3,a0,hv3); ACC4(1,3,a1,hv3); ACC4(2,3,a2,hv3);
#undef ACC4
        }
    }
}

DI void load_weights_lds(const float* __restrict__ WhT, int jb, int tid, float* __restrict__ wl)
{
    for (int q = tid; q < 12 * 128; q += 256) {
        int c = q >> 7;
        int k4 = (q & 127) * 4;
        int gate = c >> 2, j4 = c & 3;
        float4 w = *(const float4*)(WhT + ((size_t)(gate * 512 + jb + j4)) * 512 + k4);
        *(float4*)&wl[c * 580 + (k4 >> 6) * 72 + ((k4 >> 5) & 1) * 36 + (k4 & 31)] = w;
    }
}

// ---------------------------------------------------------------------------
// Persistent encoder: 256 blocks (dir = blk>>7, 4 cols each), 64 steps,
// grid barrier between steps. Weights LDS-resident.
// ---------------------------------------------------------------------------
__global__ __launch_bounds__(256, 1) void enc_persistent_kernel(
    const float* __restrict__ WhT_f, const float* __restrict__ WhT_b,
    const float* __restrict__ bh_f, const float* __restrict__ bh_b,
    const float* __restrict__ giF, const float* __restrict__ giB,
    const int* __restrict__ src_lens,
    float* __restrict__ hF, float* __restrict__ hB,
    float* __restrict__ wrep, float* __restrict__ sent, unsigned* __restrict__ bar)
{
    __shared__ float wl[6960];
    __shared__ float hl[9344];
    const int tid = threadIdx.x;
    const int dir = blockIdx.x >> 7;
    const int jb = (blockIdx.x & 127) * 4;
    const int bq = tid >> 5, jj = (tid >> 3) & 3, kseg = tid & 7;
    const int j = jb + jj;
    const float* WhT = dir ? WhT_b : WhT_f;
    const float* gi  = dir ? giB : giF;
    const float* bhp = dir ? bh_b : bh_f;
    float* hping = dir ? hB : hF;

    load_weights_lds(WhT, jb, tid, wl);
    float bh0 = 0.f, bh1 = 0.f, bh2 = 0.f;
    int len[4] = {1,1,1,1};
    if (kseg == 0) {
        bh0 = bhp[j]; bh1 = bhp[512 + j]; bh2 = bhp[1024 + j];
        #pragma unroll
        for (int i = 0; i < 4; i++) { int l = src_lens[bq * 4 + i]; len[i] = l < 1 ? 1 : l; }
    }

    for (int step = 0; step < 64; step++) {
        const float* hin = hping + (step & 1) * 16384;
        float* hout = hping + ((step + 1) & 1) * 16384;
        float acc[3][4] = {};
        recur_mm(hin, wl, hl, tid, jj, kseg, bq, acc);
        #pragma unroll
        for (int g = 0; g < 3; g++)
            #pragma unroll
            for (int i = 0; i < 4; i++) {
                float v = acc[g][i];
                v += __shfl_xor(v, 1); v += __shfl_xor(v, 2); v += __shfl_xor(v, 4);
                acc[g][i] = v;
            }
        const int t_eff = dir ? (63 - step) : step;
        if (kseg == 0) {
            #pragma unroll
            for (int i = 0; i < 4; i++) {
                int b = bq * 4 + i;
                size_t gb = ((size_t)b * 64 + t_eff) * 1536 + j;
                float hprev = hin[b * 512 + j];
                float hnew = gru_out(gi[gb], gi[gb + 512], gi[gb + 1024],
                                     acc[0][i], acc[1][i], acc[2][i],
                                     bh0, bh1, bh2, hprev);
                bool valid = t_eff < len[i];
                float hkeep = valid ? hnew : hprev;
                hout[b * 512 + j] = hkeep;
                wrep[((size_t)b * 64 + t_eff) * 1024 + dir * 512 + j] = valid ? hnew : 0.f;
                if (step == 63) sent[b * 1024 + dir * 512 + j] = hkeep;
            }
        }
        grid_barrier(bar, step, 256u);
    }
}

// ---------------------------------------------------------------------------
// Persistent decoder: 128 blocks, 63 steps, 2 barriers/step.
// Phase 1 (all blocks): h = GRU(e, hid_prev) via LDS weights.
// Phase 2 (blocks 0..31, one per batch): q/scores/softmax/attn, hid write.
// ---------------------------------------------------------------------------
__global__ __launch_bounds__(256, 1) void dec_persistent_kernel(
    const float* __restrict__ WhT_d, const float* __restrict__ bh_d,
    const float* __restrict__ giD,
    const float* __restrict__ Kmat, const float* __restrict__ Vmat,
    const float* __restrict__ Wq, const float* __restrict__ bqv,
    float* __restrict__ HID, float* __restrict__ htmp, unsigned* __restrict__ bar)
{
    __shared__ float wl[6960];
    __shared__ float hl[9344];
    const int tid = threadIdx.x;
    const int jb = blockIdx.x * 4;
    const int bq = tid >> 5, jj = (tid >> 3) & 3, kseg = tid & 7;
    const int j = jb + jj;

    load_weights_lds(WhT_d, jb, tid, wl);
    float bh0 = 0.f, bh1 = 0.f, bh2 = 0.f;
    if (kseg == 0) { bh0 = bh_d[j]; bh1 = bh_d[512 + j]; bh2 = bh_d[1024 + j]; }

    for (int t = 0; t < 63; t++) {
        const float* hin = HID + (size_t)t * 16384;
        float acc[3][4] = {};
        recur_mm(hin, wl, hl, tid, jj, kseg, bq, acc);
        #pragma unroll
        for (int g = 0; g < 3; g++)
            #pragma unroll
            for (int i = 0; i < 4; i++) {
                float v = acc[g][i];
                v += __shfl_xor(v, 1); v += __shfl_xor(v, 2); v += __shfl_xor(v, 4);
                acc[g][i] = v;
            }
        if (kseg == 0) {
            #pragma unroll
            for (int i = 0; i < 4; i++) {
                int b = bq * 4 + i;
                size_t gb = ((size_t)t * 32 + b) * 1536 + j;
                float hprev = hin[b * 512 + j];
                float hnew = gru_out(giD[gb], giD[gb + 512], giD[gb + 1024],
                                     acc[0][i], acc[1][i], acc[2][i],
                                     bh0, bh1, bh2, hprev);
                htmp[b * 512 + j] = hnew;
            }
        }
        grid_barrier(bar, 2 * t, 128u);

        if (blockIdx.x < 32) {
            const int b = blockIdx.x;
            float* Kt  = hl;          // 64 x 68
            float* hl2 = hl + 4352;   // 512
            float* qv  = hl + 4864;   // 64
            float* aw  = hl + 4928;   // 64
            #pragma unroll
            for (int it = 0; it < 4; it++) {
                int q = tid + it * 256;
                int s = q >> 4, d = (q & 15) * 4;
                float4 v = *(const float4*)(Kmat + ((size_t)b * 64 + s) * 64 + d);
                *(float4*)&Kt[s * 68 + d] = v;
            }
            if (tid < 128) {
                float4 v = *(const float4*)(htmp + b * 512 + tid * 4);
                *(float4*)&hl2[tid * 4] = v;
            }
            __syncthreads();
            {
                int o = tid >> 2, part = tid & 3;
                float a = 0.f;
                const float* wqp = Wq + (size_t)(part * 128) * 64 + o;
                const float* hp = hl2 + part * 128;
                #pragma unroll 4
                for (int k = 0; k < 128; k++) a = fmaf(hp[k], wqp[(size_t)k * 64], a);
                a += __shfl_xor(a, 1); a += __shfl_xor(a, 2);
                if (part == 0) qv[o] = a + bqv[o];
            }
            __syncthreads();
            if (tid < 64) {
                float sc = 0.f;
                #pragma unroll 8
                for (int d = 0; d < 64; d++) sc = fmaf(qv[d], Kt[tid * 68 + d], sc);
                sc *= 0.125f;
                float mx = sc;
                #pragma unroll
                for (int m = 32; m >= 1; m >>= 1) mx = fmaxf(mx, __shfl_xor(mx, m));
                float e = expf(sc - mx);
                float sm = e;
                #pragma unroll
                for (int m = 32; m >= 1; m >>= 1) sm += __shfl_xor(sm, m);
                aw[tid] = e / sm;
            }
            __syncthreads();
            float* hid = HID + (size_t)(t + 1) * 16384 + (size_t)b * 512;
            #pragma unroll
            for (int c = 0; c < 2; c++) {
                int col = tid + c * 256;
                float a = 0.f;
                #pragma unroll 4
                for (int s = 0; s < 64; s++) a = fmaf(aw[s], Vmat[((size_t)b * 64 + s) * 512 + col], a);
                hid[col] = hl2[col] + a;
            }
        }
        grid_barrier(bar, 2 * t + 1, 128u);
    }
}

// out[:, 0, :] = 0
__global__ __launch_bounds__(256) void zero_col0_kernel(float* __restrict__ out)
{
    int gid = blockIdx.x * 256 + threadIdx.x;
    if (gid < 32 * 32000) {
        int b = gid / 32000, col = gid % 32000;
        out[(size_t)b * 64 * 32000 + col] = 0.f;
    }
}

// ---------------------------------------------------------------------------
extern "C" void kernel_launch(void* const* d_in, const int* in_sizes, int n_in,
                              void* d_out, int out_size, void* d_ws, size_t ws_size,
                              hipStream_t stream)
{
    const int*   src       = (const int*)d_in[0];
    const int*   trg       = (const int*)d_in[1];
    const int*   src_lens  = (const int*)d_in[2];
    const float* enc_embed = (const float*)d_in[3];
    const float* Wi_f  = (const float*)d_in[4];
    const float* Wh_f  = (const float*)d_in[5];
    const float* bi_f  = (const float*)d_in[6];
    const float* bh_f  = (const float*)d_in[7];
    const float* Wi_b  = (const float*)d_in[8];
    const float* Wh_b  = (const float*)d_in[9];
    const float* bi_b  = (const float*)d_in[10];
    const float* bh_b  = (const float*)d_in[11];
    const float* W_e2d = (const float*)d_in[12];
    const float* b_e2d = (const float*)d_in[13];
    const float* dec_embed = (const float*)d_in[14];
    const float* Wi_d  = (const float*)d_in[15];
    const float* Wh_d  = (const float*)d_in[16];
    const float* bi_d  = (const float*)d_in[17];
    const float* bh_d  = (const float*)d_in[18];
    const float* Wq    = (const float*)d_in[19];
    const float* bq    = (const float*)d_in[20];
    const float* Wk    = (const float*)d_in[21];
    const float* bk    = (const float*)d_in[22];
    const float* Wv    = (const float*)d_in[23];
    const float* bv    = (const float*)d_in[24];
    const float* W1    = (const float*)d_in[25];
    const float* b1    = (const float*)d_in[26];
    const float* W2    = (const float*)d_in[27];
    const float* b2    = (const float*)d_in[28];
    float* out = (float*)d_out;

    // workspace layout
    float* f = (float*)d_ws;
    float* embE = f; f += 524288;     // 2048 x 256
    float* embD = f; f += 516096;     // 2016 x 256
    float* giF  = f; f += 3145728;    // 2048 x 1536
    float* giB  = f; f += 3145728;
    float* giD  = f; f += 3096576;    // 2016 x 1536
    float* wrep = f; f += 2097152;    // 2048 x 1024
    float* sent = f; f += 32768;      // 32 x 1024
    float* hF   = f; f += 32768;      // 2 x 32 x 512 ping-pong
    float* hB   = f; f += 32768;
    float* Kmat = f; f += 131072;     // 2048 x 64
    float* Vmat = f; f += 1048576;    // 2048 x 512
    float* HID  = f; f += 1048576;    // 64 x 32 x 512
    float* htmp = f; f += 16384;      // 32 x 512
    float* G1   = f; f += 1032192;    // 2016 x 512
    float* WhTf = f; f += 786432;     // 1536 x 512
    float* WhTb = f; f += 786432;
    float* WhTd = f; f += 786432;
    unsigned* bar = (unsigned*)f; f += 256;
    u16* u = (u16*)f;
    u16* WiF_hi = u; u += 393216;  u16* WiF_lo = u; u += 393216;
    u16* WiB_hi = u; u += 393216;  u16* WiB_lo = u; u += 393216;
    u16* WiD_hi = u; u += 393216;  u16* WiD_lo = u; u += 393216;
    u16* Wk_hi  = u; u += 65536;   u16* Wk_lo  = u; u += 65536;
    u16* Wv_hi  = u; u += 524288;  u16* Wv_lo  = u; u += 524288;
    u16* We_hi  = u; u += 524288;  u16* We_lo  = u; u += 524288;
    u16* W1_hi  = u; u += 262144;  u16* W1_lo  = u; u += 262144;
    u16* W2_hi  = u; u += 16384000; u16* W2_lo = u; u += 16384000;

    // --- weight prep ---
    hipLaunchKernelGGL(transpose_split_kernel, dim3(48, 8),   dim3(256), 0, stream, Wi_f,  WiF_hi, WiF_lo, 256, 1536);
    hipLaunchKernelGGL(transpose_split_kernel, dim3(48, 8),   dim3(256), 0, stream, Wi_b,  WiB_hi, WiB_lo, 256, 1536);
    hipLaunchKernelGGL(transpose_split_kernel, dim3(48, 8),   dim3(256), 0, stream, Wi_d,  WiD_hi, WiD_lo, 256, 1536);
    hipLaunchKernelGGL(transpose_split_kernel, dim3(2, 32),   dim3(256), 0, stream, Wk,    Wk_hi,  Wk_lo,  1024, 64);
    hipLaunchKernelGGL(transpose_split_kernel, dim3(16, 32),  dim3(256), 0, stream, Wv,    Wv_hi,  Wv_lo,  1024, 512);
    hipLaunchKernelGGL(transpose_split_kernel, dim3(16, 32),  dim3(256), 0, stream, W_e2d, We_hi,  We_lo,  1024, 512);
    hipLaunchKernelGGL(transpose_split_kernel, dim3(16, 16),  dim3(256), 0, stream, W1,    W1_hi,  W1_lo,  512, 512);
    hipLaunchKernelGGL(transpose_split_kernel, dim3(1000, 16),dim3(256), 0, stream, W2,    W2_hi,  W2_lo,  512, 32000);
    hipLaunchKernelGGL(transpose_f32_kernel,   dim3(48, 16),  dim3(256), 0, stream, Wh_f,  WhTf, 512, 1536);
    hipLaunchKernelGGL(transpose_f32_kernel,   dim3(48, 16),  dim3(256), 0, stream, Wh_b,  WhTb, 512, 1536);
    hipLaunchKernelGGL(transpose_f32_kernel,   dim3(48, 16),  dim3(256), 0, stream, Wh_d,  WhTd, 512, 1536);

    // --- gathers + zero h + zero barriers ---
    hipLaunchKernelGGL(gather_init_kernel, dim3(4193), dim3(256), 0, stream,
                       src, trg, enc_embed, dec_embed, embE, embD, hF, hB, bar);

    // --- input projections (batched over all timesteps) ---
    hipLaunchKernelGGL(gemm_bf16x3_kernel, dim3(12, 16), dim3(256), 0, stream,
                       embE, WiF_hi, WiF_lo, bi_f, giF, 2048, 1536, 256, 0, 0);
    hipLaunchKernelGGL(gemm_bf16x3_kernel, dim3(12, 16), dim3(256), 0, stream,
                       embE, WiB_hi, WiB_lo, bi_b, giB, 2048, 1536, 256, 0, 0);
    hipLaunchKernelGGL(gemm_bf16x3_kernel, dim3(12, 16), dim3(256), 0, stream,
                       embD, WiD_hi, WiD_lo, bi_d, giD, 2016, 1536, 256, 0, 0);

    // --- encoder: one persistent launch ---
    hipLaunchKernelGGL(enc_persistent_kernel, dim3(256), dim3(256), 0, stream,
                       WhTf, WhTb, bh_f, bh_b, giF, giB, src_lens,
                       hF, hB, wrep, sent, bar);

    // --- K/V projections, decoder init state ---
    hipLaunchKernelGGL(gemm_bf16x3_kernel, dim3(1, 16), dim3(256), 0, stream,
                       wrep, Wk_hi, Wk_lo, bk, Kmat, 2048, 64, 1024, 0, 0);
    hipLaunchKernelGGL(gemm_bf16x3_kernel, dim3(4, 16), dim3(256), 0, stream,
                       wrep, Wv_hi, Wv_lo, bv, Vmat, 2048, 512, 1024, 0, 0);
    hipLaunchKernelGGL(gemm_bf16x3_kernel, dim3(4, 1), dim3(256), 0, stream,
                       sent, We_hi, We_lo, b_e2d, HID, 32, 512, 1024, 1, 0);

    // --- decoder: one persistent launch ---
    hipLaunchKernelGGL(dec_persistent_kernel, dim3(128), dim3(256), 0, stream,
                       WhTd, bh_d, giD, Kmat, Vmat, Wq, bq, HID, htmp, bar + 64);

    // --- output projection ---
    hipLaunchKernelGGL(gemm_bf16x3_kernel, dim3(4, 16), dim3(256), 0, stream,
                       HID + 16384, W1_hi, W1_lo, b1, G1, 2016, 512, 512, 1, 0);
    hipLaunchKernelGGL(gemm_bf16x3_kernel, dim3(250, 16), dim3(256), 0, stream,
                       G1, W2_hi, W2_lo, b2, out, 2016, 32000, 512, 0, 1);

    hipLaunchKernelGGL(zero_col0_kernel, dim3(4000), dim3(256), 0, stream, out);
}